// Round 4
// baseline (1616.569 us; speedup 1.0000x reference)
//
#include <hip/hip_runtime.h>

// v4: rolling-row implicit-GEMM conv3x3(64->256) + bias + GELU + mean.
// Block = (n, group of 9 output rows); grid 64*14 = 896 blocks, 512 threads.
// 4-slot rolling LDS window xs[4][128][64] bf16 (exactly 64KB -> 2 blocks/CU):
// stage ONE new input row per iteration (vs 3 in v3), one barrier per row.
// Staging loads are issued before the tap loop and converted after it so HBM
// latency hides under the 288 MFMAs. Bank-conflict-free via ci-block rotation
// swizzle blk_eff=(blk+col)&7 (128B col stride -> bank depends only on
// blk_eff; writes hit all 32 banks per 8 lanes, reads are free 2-way; the
// swizzle is invariant to pf*16 and pixBase mod 8 so B-read bases are 6
// precomputed offsets). Weights (wb2, fragment-linear bf16) and the per-row
// epilogue (bias+GELU+mask+shuffle+atomicAdd into prep-zeroed out) as v3.

typedef __attribute__((ext_vector_type(8))) short short8;
typedef __attribute__((ext_vector_type(4))) float floatx4;
typedef __attribute__((ext_vector_type(4))) unsigned int uintx4;

#define NGRP 14
#define LROWS 9

__device__ __forceinline__ unsigned int f2bf(float f) {
    unsigned int u = __float_as_uint(f);
    return (u + 0x7FFFu + ((u >> 16) & 1u)) >> 16;   // RNE
}

__device__ __forceinline__ float gelu_t(float y) {
    // gelu(y) = y * sigmoid(2*0.7978845608*(y + 0.044715 y^3))
    float p = __builtin_fmaf(0.044715f, y * y, 1.0f);
    float e = exp2f(-2.3022084f * y * p);
    return y * __builtin_amdgcn_rcpf(1.0f + e);
}

__global__ __launch_bounds__(256)
void prep_kernel(const float* __restrict__ wgt, float* __restrict__ out,
                 unsigned short* __restrict__ wb2) {
    int g = blockIdx.x * 256 + threadIdx.x;
    if (g < 64 * 256) out[g] = 0.f;               // zero the atomic target
    if (g < 147456) {                             // 9 taps * 2 halves * 16 cog * 64 lane * 8
        int j    = g & 7;
        int lane = (g >> 3) & 63;
        int fc   = g >> 9;
        int cog  = fc & 15;
        int half = (fc >> 4) & 1;
        int tap  = fc >> 5;
        int li = lane & 15, quad = lane >> 4;
        int co = cog * 16 + li;
        int ci = half * 32 + quad * 8 + j;
        wb2[g] = (unsigned short)f2bf(wgt[(co * 64 + ci) * 9 + tap]);
    }
}

__global__ __launch_bounds__(512, 4)
void conv_kernel(const float* __restrict__ x, const float* __restrict__ bias,
                 const unsigned short* __restrict__ wb2, float* __restrict__ out) {
    __shared__ unsigned short xs[4][128][64];     // exactly 65536 B -> 2 blocks/CU
    unsigned short* xsf = &xs[0][0][0];

    const int bx = blockIdx.x;
    const int n  = bx / NGRP;
    const int R0 = (bx % NGRP) * LROWS;
    const int tid  = threadIdx.x;
    const int lane = tid & 63;
    const int wave = tid >> 6;
    const int li   = lane & 15;
    const int quad = lane >> 4;
    const int sc = wave & 3;
    const int sp = wave >> 2;
    const int coBase  = sc * 64;
    const int pixBase = sp * 64;

    // ---- staging mapping: thread (col, cig) handles ci = cig*16 .. +15 ----
    const int col = tid & 127;
    const int cig = tid >> 7;
    const float* xg = x + (size_t)n * 64 * 16384 + (size_t)cig * 16 * 16384 + col;
    const int w0 = col * 64 + (((cig * 2    ) + col) & 7) * 8;   // swizzled blk slots
    const int w1 = col * 64 + (((cig * 2 + 1) + col) & 7) * 8;

    // ---- B-read base offsets (shorts) per (kw,hf); pf adds pf*1024 ----
    int boff[3][2];
#pragma unroll
    for (int kw = 0; kw < 3; ++kw)
#pragma unroll
        for (int hf = 0; hf < 2; ++hf)
            boff[kw][hf] = (pixBase + li + kw) * 64
                         + ((hf * 4 + quad + kw + li) & 7) * 8;

    const unsigned short* abase = wb2 + (size_t)(sc * 4) * 512 + lane * 8;

    // ---- prologue: stage rows R0..R0+2 into slots 0..2 ----
#pragma unroll
    for (int r = 0; r < 3; ++r) {
        float v[16];
#pragma unroll
        for (int k = 0; k < 16; ++k)
            v[k] = xg[(size_t)(R0 + r) * 128 + (size_t)k * 16384];
        uintx4 p0, p1;
#pragma unroll
        for (int j = 0; j < 4; ++j) {
            p0[j] = f2bf(v[2*j])     | (f2bf(v[2*j+1]) << 16);
            p1[j] = f2bf(v[8+2*j])   | (f2bf(v[9+2*j]) << 16);
        }
        *reinterpret_cast<uintx4*>(xsf + r * 8192 + w0) = p0;
        *reinterpret_cast<uintx4*>(xsf + r * 8192 + w1) = p1;
    }

    int sA = 0, sB = 8192, sC = 16384, sD = 24576;  // slot offsets (shorts)
    __syncthreads();

    const float inv = 1.0f / (126.f * 126.f);
    union Frag { uintx4 u; short8 s; };

#pragma unroll 1
    for (int h = 0; h < LROWS; ++h) {
        // issue next row's loads now; convert after compute (latency hidden)
        float v[16];
        const bool do_stage = (h < LROWS - 1);
        if (do_stage) {
#pragma unroll
            for (int k = 0; k < 16; ++k)
                v[k] = xg[(size_t)(R0 + h + 3) * 128 + (size_t)k * 16384];
        }

        floatx4 acc[16];                          // [cf][pf]
#pragma unroll
        for (int i = 0; i < 16; ++i) acc[i] = (floatx4){0.f, 0.f, 0.f, 0.f};

        const int sk[3] = { sA, sB, sC };         // slot of input row R0+h+kh
#pragma unroll
        for (int tap = 0; tap < 9; ++tap) {
            const int kh = tap / 3, kw = tap % 3;
            const int sb = sk[kh];
#pragma unroll
            for (int hf = 0; hf < 2; ++hf) {
                Frag a[4];
#pragma unroll
                for (int cf = 0; cf < 4; ++cf)
                    a[cf].u = *reinterpret_cast<const uintx4*>(
                        abase + (size_t)(((tap * 2 + hf) * 16) + cf) * 512);
#pragma unroll
                for (int pf = 0; pf < 4; ++pf) {
                    Frag b;
                    b.u = *reinterpret_cast<const uintx4*>(
                        xsf + sb + boff[kw][hf] + pf * 1024);     // ds_read_b128
#pragma unroll
                    for (int cf = 0; cf < 4; ++cf)
                        acc[cf * 4 + pf] = __builtin_amdgcn_mfma_f32_16x16x32_bf16(
                            a[cf].s, b.s, acc[cf * 4 + pf], 0, 0, 0);
                }
            }
        }

        // stage write: cvt + 2x ds_write_b128 (conflict-free swizzle)
        if (do_stage) {
            uintx4 p0, p1;
#pragma unroll
            for (int j = 0; j < 4; ++j) {
                p0[j] = f2bf(v[2*j])   | (f2bf(v[2*j+1]) << 16);
                p1[j] = f2bf(v[8+2*j]) | (f2bf(v[9+2*j]) << 16);
            }
            *reinterpret_cast<uintx4*>(xsf + sD + w0) = p0;
            *reinterpret_cast<uintx4*>(xsf + sD + w1) = p1;
        }

        // per-row epilogue: bias + GELU + mask + 16-lane reduce + atomic mean
#pragma unroll
        for (int cf = 0; cf < 4; ++cf) {
            const floatx4 bv = *reinterpret_cast<const floatx4*>(
                bias + coBase + cf * 16 + quad * 4);
            floatx4 s = (floatx4){0.f, 0.f, 0.f, 0.f};
#pragma unroll
            for (int pf = 0; pf < 4; ++pf) {
                bool valid = (pixBase + pf * 16 + li) < 126;
#pragma unroll
                for (int r = 0; r < 4; ++r) {
                    float gv = gelu_t(acc[cf * 4 + pf][r] + bv[r]);
                    s[r] += valid ? gv : 0.f;     // select contains masked-col garbage
                }
            }
#pragma unroll
            for (int r = 0; r < 4; ++r) {
                float vv = s[r];
                vv += __shfl_xor(vv, 1);
                vv += __shfl_xor(vv, 2);
                vv += __shfl_xor(vv, 4);
                vv += __shfl_xor(vv, 8);
                if (li == 0)
                    atomicAdd(&out[n * 256 + coBase + cf * 16 + quad * 4 + r], vv * inv);
            }
        }

        __syncthreads();                          // gates slot reuse + stage visibility
        int t = sA; sA = sB; sB = sC; sC = sD; sD = t;
    }
}

extern "C" void kernel_launch(void* const* d_in, const int* in_sizes, int n_in,
                              void* d_out, int out_size, void* d_ws, size_t ws_size,
                              hipStream_t stream) {
    const float* x    = (const float*)d_in[0];
    const float* wgt  = (const float*)d_in[1];
    const float* bias = (const float*)d_in[2];
    float* out = (float*)d_out;
    unsigned short* wb2 = (unsigned short*)d_ws;  // 294912 B, fragment-linear bf16

    prep_kernel<<<576, 256, 0, stream>>>(wgt, out, wb2);
    conv_kernel<<<64 * NGRP, 512, 0, stream>>>(x, bias, wb2, out);
}